// Round 1
// baseline (607.919 us; speedup 1.0000x reference)
//
#include <hip/hip_runtime.h>
#include <math.h>

// Problem constants: q,k,v are [B=2, H=16, N=2048, Dh=64] fp32.
#define BH 32
#define NN 2048
#define DD 64
#define SCALE 8.0f

// Tiling
#define TN 64    // rows (n) per block  in stats kernel / per iteration in wsum
#define TM 128   // cols (m) per tile
#define QPAD 68  // 64 + 4: keeps rows 16B-aligned for float4 LDS reads, <=2-way banks
#define KPAD 68

// ---------------------------------------------------------------------------
// Phase 1: per-row softmax stats (max, sum-exp) via online softmax.
// Grid: (N/TN, BH). Block: 256 threads = (tx 0..15) x (ty 0..15).
// Thread owns rows {ty+16i} (i<4) and cols {tx+16j} (j<8) of the 64x128 tile.
// ---------------------------------------------------------------------------
__global__ __launch_bounds__(256) void stats_kernel(const float* __restrict__ q,
                                                    const float* __restrict__ k,
                                                    float* __restrict__ smax,
                                                    float* __restrict__ sden) {
    __shared__ float Qs[TN][QPAD];
    __shared__ float Ks[TM][KPAD];

    const int bh  = blockIdx.y;
    const int n0  = blockIdx.x * TN;
    const int tid = threadIdx.x;
    const int tx  = tid & 15;
    const int ty  = tid >> 4;
    const size_t base = (size_t)bh * NN * DD;

    // Load Q tile (pre-scaled by SCALE so acc == logits directly).
    for (int t = tid; t < TN * DD; t += 256) {
        int r = t >> 6, d = t & 63;
        Qs[r][d] = SCALE * q[base + (size_t)(n0 + r) * DD + d];
    }

    float m_run[4] = {-INFINITY, -INFINITY, -INFINITY, -INFINITY};
    float d_run[4] = {0.f, 0.f, 0.f, 0.f};

    for (int mt = 0; mt < NN / TM; ++mt) {
        const int m0 = mt * TM;
        __syncthreads();  // protect Ks from previous iteration's readers (also Qs @ mt=0)
        for (int t = tid; t < TM * DD; t += 256) {
            int r = t >> 6, d = t & 63;
            Ks[r][d] = k[base + (size_t)(m0 + r) * DD + d];
        }
        __syncthreads();

        float acc[4][8];
#pragma unroll
        for (int i = 0; i < 4; ++i)
#pragma unroll
            for (int j = 0; j < 8; ++j) acc[i][j] = 0.f;

#pragma unroll
        for (int d = 0; d < DD; d += 4) {
            float4 qv[4], kv[8];
#pragma unroll
            for (int i = 0; i < 4; ++i)
                qv[i] = *(const float4*)&Qs[ty + 16 * i][d];
#pragma unroll
            for (int j = 0; j < 8; ++j)
                kv[j] = *(const float4*)&Ks[tx + 16 * j][d];
#pragma unroll
            for (int i = 0; i < 4; ++i)
#pragma unroll
                for (int j = 0; j < 8; ++j) {
                    acc[i][j] = fmaf(qv[i].x, kv[j].x, acc[i][j]);
                    acc[i][j] = fmaf(qv[i].y, kv[j].y, acc[i][j]);
                    acc[i][j] = fmaf(qv[i].z, kv[j].z, acc[i][j]);
                    acc[i][j] = fmaf(qv[i].w, kv[j].w, acc[i][j]);
                }
        }

        // Online softmax stats per row: reduce over 8 local cols + 16 tx-lanes.
#pragma unroll
        for (int i = 0; i < 4; ++i) {
            float tmax = acc[i][0];
#pragma unroll
            for (int j = 1; j < 8; ++j) tmax = fmaxf(tmax, acc[i][j]);
            for (int off = 1; off < 16; off <<= 1)
                tmax = fmaxf(tmax, __shfl_xor(tmax, off));
            float m_new = fmaxf(m_run[i], tmax);
            float s = 0.f;
#pragma unroll
            for (int j = 0; j < 8; ++j) s += __expf(acc[i][j] - m_new);
            for (int off = 1; off < 16; off <<= 1)
                s += __shfl_xor(s, off);
            d_run[i] = d_run[i] * __expf(m_run[i] - m_new) + s;
            m_run[i] = m_new;
        }
    }

    if (tx == 0) {
#pragma unroll
        for (int i = 0; i < 4; ++i) {
            int r = n0 + ty + 16 * i;
            smax[(size_t)bh * NN + r] = m_run[i];
            sden[(size_t)bh * NN + r] = d_run[i];
        }
    }
}

// ---------------------------------------------------------------------------
// Phase 2: w[m] = sum_n exp(s[n,m]-max_n)/den_n. Block owns 128 cols (K tile
// loaded once), iterates all row tiles, accumulates column sums in registers.
// Grid: (N/TM, BH). No atomics: each block exclusively owns its 128 m's.
// ---------------------------------------------------------------------------
__global__ __launch_bounds__(256) void wsum_kernel(const float* __restrict__ q,
                                                   const float* __restrict__ k,
                                                   const float* __restrict__ smax,
                                                   const float* __restrict__ sden,
                                                   float* __restrict__ w) {
    __shared__ float Qs[TN][QPAD];
    __shared__ float Ks[TM][KPAD];

    const int bh  = blockIdx.y;
    const int m0  = blockIdx.x * TM;
    const int tid = threadIdx.x;
    const int tx  = tid & 15;
    const int ty  = tid >> 4;
    const size_t base = (size_t)bh * NN * DD;

    for (int t = tid; t < TM * DD; t += 256) {
        int r = t >> 6, d = t & 63;
        Ks[r][d] = k[base + (size_t)(m0 + r) * DD + d];
    }

    float wacc[8] = {0.f, 0.f, 0.f, 0.f, 0.f, 0.f, 0.f, 0.f};

    for (int nt = 0; nt < NN / TN; ++nt) {
        const int n0 = nt * TN;
        __syncthreads();  // protect Qs from previous iteration's readers (also Ks @ nt=0)
        for (int t = tid; t < TN * DD; t += 256) {
            int r = t >> 6, d = t & 63;
            Qs[r][d] = SCALE * q[base + (size_t)(n0 + r) * DD + d];
        }
        __syncthreads();

        float acc[4][8];
#pragma unroll
        for (int i = 0; i < 4; ++i)
#pragma unroll
            for (int j = 0; j < 8; ++j) acc[i][j] = 0.f;

#pragma unroll
        for (int d = 0; d < DD; d += 4) {
            float4 qv[4], kv[8];
#pragma unroll
            for (int i = 0; i < 4; ++i)
                qv[i] = *(const float4*)&Qs[ty + 16 * i][d];
#pragma unroll
            for (int j = 0; j < 8; ++j)
                kv[j] = *(const float4*)&Ks[tx + 16 * j][d];
#pragma unroll
            for (int i = 0; i < 4; ++i)
#pragma unroll
                for (int j = 0; j < 8; ++j) {
                    acc[i][j] = fmaf(qv[i].x, kv[j].x, acc[i][j]);
                    acc[i][j] = fmaf(qv[i].y, kv[j].y, acc[i][j]);
                    acc[i][j] = fmaf(qv[i].z, kv[j].z, acc[i][j]);
                    acc[i][j] = fmaf(qv[i].w, kv[j].w, acc[i][j]);
                }
        }

#pragma unroll
        for (int i = 0; i < 4; ++i) {
            int r = n0 + ty + 16 * i;
            float rm  = smax[(size_t)bh * NN + r];
            float rdi = 1.0f / sden[(size_t)bh * NN + r];
#pragma unroll
            for (int j = 0; j < 8; ++j)
                wacc[j] += __expf(acc[i][j] - rm) * rdi;
        }
    }

    // Reduce wacc across the 16 ty-groups (cross-wave) via LDS (reuse Qs).
    __syncthreads();
    float* wp = &Qs[0][0];  // 16 x 128 scratch
#pragma unroll
    for (int j = 0; j < 8; ++j) wp[ty * TM + (tx + 16 * j)] = wacc[j];
    __syncthreads();
    for (int c = tid; c < TM; c += 256) {
        float s = 0.f;
#pragma unroll
        for (int t = 0; t < 16; ++t) s += wp[t * TM + c];
        w[(size_t)bh * NN + m0 + c] = s;
    }
}

// ---------------------------------------------------------------------------
// Phase 3: out[b,h,m,d] = w[b,h,m] * v[b,h,m,d]  (float4, memory-bound)
// ---------------------------------------------------------------------------
__global__ __launch_bounds__(256) void out_kernel(const float* __restrict__ v,
                                                  const float* __restrict__ w,
                                                  float* __restrict__ out) {
    size_t gid = (size_t)blockIdx.x * 256 + threadIdx.x;  // float4 index
    const float4* v4 = (const float4*)v;
    float4* o4 = (float4*)out;
    float4 vv = v4[gid];
    float ww = w[gid >> 4];  // 16 float4s per (b,h,m) row of 64 floats
    o4[gid] = make_float4(vv.x * ww, vv.y * ww, vv.z * ww, vv.w * ww);
}

extern "C" void kernel_launch(void* const* d_in, const int* in_sizes, int n_in,
                              void* d_out, int out_size, void* d_ws, size_t ws_size,
                              hipStream_t stream) {
    const float* q = (const float*)d_in[0];
    const float* k = (const float*)d_in[1];
    const float* v = (const float*)d_in[2];
    float* out = (float*)d_out;

    // Workspace layout (all fully overwritten every launch; poison-safe):
    float* smax = (float*)d_ws;            // BH*NN
    float* sden = smax + (size_t)BH * NN;  // BH*NN
    float* w    = sden + (size_t)BH * NN;  // BH*NN

    stats_kernel<<<dim3(NN / TN, BH), 256, 0, stream>>>(q, k, smax, sden);
    wsum_kernel<<<dim3(NN / TM, BH), 256, 0, stream>>>(q, k, smax, sden, w);
    out_kernel<<<(BH * NN * DD / 4) / 256, 256, 0, stream>>>(v, w, out);
}

// Round 2
// 281.914 us; speedup vs baseline: 2.1564x; 2.1564x over previous
//
#include <hip/hip_runtime.h>
#include <math.h>

// q,k,v: [B=2, H=16, N=2048, Dh=64] fp32.  BH = 32 independent heads.
#define BH 32
#define NN 2048
#define DD 64
#define LDK 72   // padded LDS row length (bf16 elems): stride 144B -> uniform bank use

typedef __attribute__((ext_vector_type(8)))  short shortx8;
typedef __attribute__((ext_vector_type(16))) float floatx16;

// ---- bf16 split helpers (round-to-nearest-even) ------------------------------
__device__ inline unsigned short bf16_rn(float f) {
    unsigned int u = __builtin_bit_cast(unsigned int, f);
    u += 0x7fffu + ((u >> 16) & 1u);
    return (unsigned short)(u >> 16);
}
__device__ inline float bf16_to_f(unsigned short h) {
    return __builtin_bit_cast(float, (unsigned int)h << 16);
}
__device__ inline void split_bf16(float f, unsigned short& h, unsigned short& l) {
    h = bf16_rn(f);
    l = bf16_rn(f - bf16_to_f(h));
}

// ---- build A-operand fragments for mfma_f32_32x32x16_bf16 --------------------
// Lane holds A[m = lane&31][k = (lane>>5)*8 + j]; 4 k-steps cover d=0..63.
// qrow_ptr -> q[row][0]. scale folded in (8.0 is a power of two: exact).
__device__ inline void build_a_frags(const float* __restrict__ qrow_ptr,
                                     int half, shortx8 ah[4], shortx8 al[4]) {
#pragma unroll
    for (int ks = 0; ks < 4; ++ks) {
        const float4* p = (const float4*)(qrow_ptr + ks * 16 + half * 8);
        float4 f0 = p[0], f1 = p[1];
        float vals[8] = {f0.x, f0.y, f0.z, f0.w, f1.x, f1.y, f1.z, f1.w};
#pragma unroll
        for (int j = 0; j < 8; ++j) {
            unsigned short h, l;
            split_bf16(vals[j] * 8.0f, h, l);
            ah[ks][j] = (short)h;
            al[ks][j] = (short)l;
        }
    }
}

// ---- stage a 128x64 K tile into LDS as bf16 hi/lo ----------------------------
__device__ inline void stage_k(const float* __restrict__ kbase, int krow0,
                               unsigned short* Khi, unsigned short* Klo, int tid) {
#pragma unroll
    for (int i = 0; i < 8; ++i) {
        int idx4 = tid + 256 * i;          // float4 index within 128x64 tile
        int r = idx4 >> 4;
        int d = (idx4 & 15) << 2;
        float4 f = *(const float4*)(kbase + (size_t)(krow0 + r) * DD + d);
        unsigned short* ph = &Khi[r * LDK + d];
        unsigned short* pl = &Klo[r * LDK + d];
        split_bf16(f.x, ph[0], pl[0]);
        split_bf16(f.y, ph[1], pl[1]);
        split_bf16(f.z, ph[2], pl[2]);
        split_bf16(f.w, ph[3], pl[3]);
    }
}

// C/D row for accumulator register r (0..15) given half = lane>>5.
__device__ inline int rowmap(int r, int half) {
    return (r & 3) + 8 * (r >> 2) + 4 * half;
}

// ---------------------------------------------------------------------------
// Phase 1: per-row (n) softmax stats via online softmax over all m.
// Grid (NN/128, BH), 256 threads (4 waves). Wave w owns rows n0+32w..+31.
// ---------------------------------------------------------------------------
__global__ __launch_bounds__(256, 2) void stats_kernel(const float* __restrict__ q,
                                                       const float* __restrict__ kk,
                                                       float* __restrict__ smax,
                                                       float* __restrict__ sden) {
    __shared__ unsigned short Khi[128 * LDK];
    __shared__ unsigned short Klo[128 * LDK];
    const int bh   = blockIdx.y;
    const int n0   = blockIdx.x * 128;
    const int tid  = threadIdx.x;
    const int wave = tid >> 6, lane = tid & 63;
    const int half = lane >> 5, l31 = lane & 31;
    const size_t base = (size_t)bh * NN * DD;

    shortx8 ah[4], al[4];
    build_a_frags(q + base + (size_t)(n0 + wave * 32 + l31) * DD, half, ah, al);

    float m_run[16], d_run[16];
#pragma unroll
    for (int r = 0; r < 16; ++r) { m_run[r] = -INFINITY; d_run[r] = 0.f; }

    for (int mt = 0; mt < NN / 128; ++mt) {
        __syncthreads();
        stage_k(kk + base, mt * 128, Khi, Klo, tid);
        __syncthreads();

        floatx16 acc[4];
#pragma unroll
        for (int t = 0; t < 4; ++t)
#pragma unroll
            for (int e = 0; e < 16; ++e) acc[t][e] = 0.f;

#pragma unroll
        for (int t = 0; t < 4; ++t) {
            const int mr = t * 32 + l31;
#pragma unroll
            for (int ks = 0; ks < 4; ++ks) {
                const int off = mr * LDK + ks * 16 + half * 8;
                shortx8 bhf = *(const shortx8*)&Khi[off];
                shortx8 blf = *(const shortx8*)&Klo[off];
                acc[t] = __builtin_amdgcn_mfma_f32_32x32x16_bf16(ah[ks], bhf, acc[t], 0, 0, 0);
                acc[t] = __builtin_amdgcn_mfma_f32_32x32x16_bf16(al[ks], bhf, acc[t], 0, 0, 0);
                acc[t] = __builtin_amdgcn_mfma_f32_32x32x16_bf16(ah[ks], blf, acc[t], 0, 0, 0);
            }
        }

        // Online stats: reduce over 4 tiles' cols + 32 lanes of the half.
#pragma unroll
        for (int r = 0; r < 16; ++r) {
            float tmax = fmaxf(fmaxf(acc[0][r], acc[1][r]), fmaxf(acc[2][r], acc[3][r]));
#pragma unroll
            for (int off = 1; off < 32; off <<= 1)
                tmax = fmaxf(tmax, __shfl_xor(tmax, off));
            float m_new = fmaxf(m_run[r], tmax);
            float s = __expf(acc[0][r] - m_new) + __expf(acc[1][r] - m_new)
                    + __expf(acc[2][r] - m_new) + __expf(acc[3][r] - m_new);
#pragma unroll
            for (int off = 1; off < 32; off <<= 1)
                s += __shfl_xor(s, off);
            d_run[r] = d_run[r] * __expf(m_run[r] - m_new) + s;
            m_run[r] = m_new;
        }
    }

    if (l31 == 0) {
#pragma unroll
        for (int r = 0; r < 16; ++r) {
            int row = n0 + wave * 32 + rowmap(r, half);
            smax[(size_t)bh * NN + row] = m_run[r];
            sden[(size_t)bh * NN + row] = d_run[r];
        }
    }
}

// ---------------------------------------------------------------------------
// Phase 2: w[m] = sum_n exp(s[n,m]-max_n)/den_n. Block owns 128 cols; K tile
// staged once; waves stride over 32-row strips, col sums kept in registers.
// ---------------------------------------------------------------------------
__global__ __launch_bounds__(256, 2) void wsum_kernel(const float* __restrict__ q,
                                                      const float* __restrict__ kk,
                                                      const float* __restrict__ smax,
                                                      const float* __restrict__ sden,
                                                      float* __restrict__ w) {
    __shared__ unsigned short Khi[128 * LDK];
    __shared__ unsigned short Klo[128 * LDK];
    __shared__ float wred[4 * 128];
    const int bh   = blockIdx.y;
    const int m0   = blockIdx.x * 128;
    const int tid  = threadIdx.x;
    const int wave = tid >> 6, lane = tid & 63;
    const int half = lane >> 5, l31 = lane & 31;
    const size_t base = (size_t)bh * NN * DD;

    stage_k(kk + base, m0, Khi, Klo, tid);
    __syncthreads();

    float wacc[4] = {0.f, 0.f, 0.f, 0.f};
    const float* sm = smax + (size_t)bh * NN;
    const float* sd = sden + (size_t)bh * NN;

    for (int ns = wave; ns < NN / 32; ns += 4) {
        const int n0s = ns * 32;
        shortx8 ah[4], al[4];
        build_a_frags(q + base + (size_t)(n0s + l31) * DD, half, ah, al);

        floatx16 acc[4];
#pragma unroll
        for (int t = 0; t < 4; ++t)
#pragma unroll
            for (int e = 0; e < 16; ++e) acc[t][e] = 0.f;

#pragma unroll
        for (int t = 0; t < 4; ++t) {
            const int mr = t * 32 + l31;
#pragma unroll
            for (int ks = 0; ks < 4; ++ks) {
                const int off = mr * LDK + ks * 16 + half * 8;
                shortx8 bhf = *(const shortx8*)&Khi[off];
                shortx8 blf = *(const shortx8*)&Klo[off];
                acc[t] = __builtin_amdgcn_mfma_f32_32x32x16_bf16(ah[ks], bhf, acc[t], 0, 0, 0);
                acc[t] = __builtin_amdgcn_mfma_f32_32x32x16_bf16(al[ks], bhf, acc[t], 0, 0, 0);
                acc[t] = __builtin_amdgcn_mfma_f32_32x32x16_bf16(ah[ks], blf, acc[t], 0, 0, 0);
            }
        }

#pragma unroll
        for (int r = 0; r < 16; ++r) {
            const int n = n0s + rowmap(r, half);
            float rm  = sm[n];
            float rdi = 1.0f / sd[n];
#pragma unroll
            for (int t = 0; t < 4; ++t)
                wacc[t] += __expf(acc[t][r] - rm) * rdi;
        }
    }

    // halves hold same cols, different rows: sum across halves, then waves.
#pragma unroll
    for (int t = 0; t < 4; ++t) wacc[t] += __shfl_xor(wacc[t], 32);
    if (half == 0) {
#pragma unroll
        for (int t = 0; t < 4; ++t) wred[wave * 128 + t * 32 + l31] = wacc[t];
    }
    __syncthreads();
    if (tid < 128) {
        float s = wred[tid] + wred[128 + tid] + wred[256 + tid] + wred[384 + tid];
        w[(size_t)bh * NN + m0 + tid] = s;
    }
}

// ---------------------------------------------------------------------------
// Phase 3: out[b,h,m,d] = w[b,h,m] * v[b,h,m,d]
// ---------------------------------------------------------------------------
__global__ __launch_bounds__(256) void out_kernel(const float* __restrict__ v,
                                                  const float* __restrict__ w,
                                                  float* __restrict__ out) {
    size_t gid = (size_t)blockIdx.x * 256 + threadIdx.x;  // float4 index
    const float4* v4 = (const float4*)v;
    float4* o4 = (float4*)out;
    float4 vv = v4[gid];
    float ww = w[gid >> 4];  // 16 float4s per 64-float row
    o4[gid] = make_float4(vv.x * ww, vv.y * ww, vv.z * ww, vv.w * ww);
}

extern "C" void kernel_launch(void* const* d_in, const int* in_sizes, int n_in,
                              void* d_out, int out_size, void* d_ws, size_t ws_size,
                              hipStream_t stream) {
    const float* q = (const float*)d_in[0];
    const float* k = (const float*)d_in[1];
    const float* v = (const float*)d_in[2];
    float* out = (float*)d_out;

    float* smax = (float*)d_ws;            // BH*NN
    float* sden = smax + (size_t)BH * NN;  // BH*NN
    float* w    = sden + (size_t)BH * NN;  // BH*NN

    stats_kernel<<<dim3(NN / 128, BH), 256, 0, stream>>>(q, k, smax, sden);
    wsum_kernel<<<dim3(NN / 128, BH), 256, 0, stream>>>(q, k, smax, sden, w);
    out_kernel<<<(BH * NN * DD / 4) / 256, 256, 0, stream>>>(v, w, out);
}